// Round 3
// baseline (7751.764 us; speedup 1.0000x reference)
//
#include <hip/hip_runtime.h>
#include <hip/hip_bf16.h>

#define BB 256
#define SS 256
#define HH 512
#define KK 512
#define MM (BB*SS)            // 65536
#define CH 32                 // timesteps per chunk
#define NCHUNK (SS/CH)        // 8
#define CHROWS (CH*BB)        // 8192 rows per chunk GEMM
#define CHSZ ((long long)CHROWS*HH)   // elements per P slot per chunk

typedef __attribute__((ext_vector_type(4))) float f32x4;
typedef __attribute__((ext_vector_type(8))) short bf16x8;   // 8 bf16 in 4 VGPRs

__device__ __forceinline__ float bf2f(unsigned short u){
  union { unsigned int i; float f; } w; w.i = ((unsigned int)u) << 16; return w.f;
}
__device__ __forceinline__ unsigned short f2bf(float f){
  union { float f; unsigned int i; } w; w.f = f;
  unsigned int x = w.i;
  x += 0x7fff + ((x >> 16) & 1);   // RNE
  return (unsigned short)(x >> 16);
}
__device__ __forceinline__ float sigf(float x){ return 1.f/(1.f+__expf(-x)); }
__device__ __forceinline__ float tanhf_(float x){
  x = fminf(fmaxf(x, -15.f), 15.f);
  float a = __expf(2.f*x);
  return (a - 1.f)/(a + 1.f);
}
__device__ __forceinline__ void gload16(const void* g, void* l){
  __builtin_amdgcn_global_load_lds(
      (const __attribute__((address_space(1))) unsigned int*)g,
      (__attribute__((address_space(3))) unsigned int*)l, 16, 0, 0);
}

// ---------------- pack x chunk -> bf16 [tl*BB+b][c] ----------------
__global__ void k_pack_x(const float* __restrict__ in, unsigned int* __restrict__ Xb32,
                         int t0){
  const long long tot2 = (long long)CHROWS*256;
  for (long long idx = (long long)blockIdx.x*blockDim.x + threadIdx.x; idx < tot2;
       idx += (long long)gridDim.x*blockDim.x){
    int r  = (int)(idx >> 8);        // tl*BB + b
    int c2 = (int)(idx & 255);       // column pair
    int b  = r & 255, tl = r >> 8;
    const float* src = in + ((long long)b*SS + t0 + tl)*514 + 2 + c2*2;
    float2 v = *(const float2*)src;
    unsigned int lo = f2bf(v.x), hi = f2bf(v.y);
    Xb32[(long long)r*256 + c2] = lo | (hi << 16);
  }
}

// ---------------- pack 12 weights, transposed to [n][k] bf16 ----------------
struct Ptr12 { const float* p[12]; };
__global__ void k_pack_w(Ptr12 ws, unsigned short* __restrict__ Wtall){
  int g = blockIdx.y;
  const float* W = ws.p[g];
  for (int idx = blockIdx.x*blockDim.x + threadIdx.x; idx < 512*512;
       idx += gridDim.x*blockDim.x){
    int n = idx >> 9, k = idx & 511;
    Wtall[(long long)g*262144 + idx] = f2bf(W[k*512 + n]);
  }
}

// ---------------- chunk GEMM, m97 structure: 128x128 tile, BK=32, global_load_lds ----------------
struct EpiArgs {
  const float *b0,*b1,*b2,*b3,*b4,*b5,*b6,*b7;
  const float *Wt1,*Wt2,*Wd1,*Wd2,*Wto,*Wdo;
};

__launch_bounds__(256)
__global__ void k_gemm1(const unsigned short* __restrict__ Xb,
                        const unsigned short* __restrict__ Wtall,
                        unsigned short* __restrict__ P,
                        EpiArgs ea, const float* __restrict__ in, int t0){
  __shared__ unsigned short As[128*32];   // [row][k] linear, 8 KB
  __shared__ unsigned short Bs[128*32];
  int tid  = threadIdx.x;
  int m0   = blockIdx.y * 128;
  int n0   = blockIdx.x * 128;         // column in 8*512 concat space (never crosses gate)
  int g    = n0 >> 9;
  int lane = tid & 63, w = tid >> 6;
  int wr = w >> 1, wc = w & 1;
  int r16  = lane & 15, kb = (lane >> 4) * 8;

  f32x4 acc[4][4] = {};
  for (int k0 = 0; k0 < KK; k0 += 32){
    __syncthreads();
#pragma unroll
    for (int q = 0; q < 2; q++){
      int idx = q*256 + tid;
      int row = idx >> 2, ko = (idx & 3) * 8;
      gload16(Xb    + (long long)(m0+row)*KK + k0 + ko, As + idx*8);
      gload16(Wtall + (long long)(n0+row)*KK + k0 + ko, Bs + idx*8);
    }
    __syncthreads();   // compiler emits vmcnt(0) drain before barrier
    bf16x8 a[4], b[4];
#pragma unroll
    for (int m = 0; m < 4; m++) a[m] = *(const bf16x8*)&As[(wr*64 + m*16 + r16)*32 + kb];
#pragma unroll
    for (int n = 0; n < 4; n++) b[n] = *(const bf16x8*)&Bs[(wc*64 + n*16 + r16)*32 + kb];
#pragma unroll
    for (int m = 0; m < 4; m++)
#pragma unroll
      for (int n = 0; n < 4; n++)
        acc[m][n] = __builtin_amdgcn_mfma_f32_16x16x32_bf16(a[m], b[n], acc[m][n], 0,0,0);
  }

  const float* biasp = (g==0)?ea.b0:(g==1)?ea.b1:(g==2)?ea.b2:(g==3)?ea.b3:
                       (g==4)?ea.b4:(g==5)?ea.b5:(g==6)?ea.b6:ea.b7;
  unsigned short* Pg = P + (long long)g*CHSZ;

  float bias_n[4], wt_a[4], wt_b[4];
#pragma unroll
  for (int n = 0; n < 4; n++){
    int h = (n0 + wc*64 + n*16 + r16) & 511;
    bias_n[n] = biasp[h];
    if (g == 3)      wt_a[n] = ea.Wt1[h];
    else if (g == 4) wt_a[n] = ea.Wt2[h];
    else if (g == 5) wt_a[n] = ea.Wd1[h];
    else if (g == 6) wt_a[n] = ea.Wd2[h];
    else if (g == 7){ wt_a[n] = ea.Wto[h]; wt_b[n] = ea.Wdo[h]; }
  }
#pragma unroll
  for (int m = 0; m < 4; m++)
#pragma unroll
    for (int i = 0; i < 4; i++){
      int rr = m0 + wr*64 + m*16 + (lane>>4)*4 + i;   // C/D row=(lane>>4)*4+reg
      float tv = 0.f, dv = 0.f;
      if (g >= 3){
        int b_ = rr & 255, tl = rr >> 8;
        long long inrow = ((long long)b_*SS + t0 + tl)*514;
        tv = in[inrow]; dv = in[inrow + 1];
      }
#pragma unroll
      for (int n = 0; n < 4; n++){
        int h = (n0 + wc*64 + n*16 + r16) & 511;
        float v = acc[m][n][i] + bias_n[n];
        if (g == 7)      v += tv*wt_a[n] + dv*wt_b[n];
        else if (g >= 3) v += sigf(((g==5||g==6) ? dv : tv) * wt_a[n]);
        Pg[(long long)rr*HH + h] = f2bf(v);
      }
    }
}

// ---------------- per-mt-group barrier (32 blocks), sense-reversing ----------------
__device__ __forceinline__ void groupbar(int* bar, int mt){
  __syncthreads();                       // all block stores issued & vmcnt-drained
  if (threadIdx.x == 0){
    int* cnt = bar + mt*64;
    int* gen = cnt + 16;
    int g0 = __hip_atomic_load(gen, __ATOMIC_RELAXED, __HIP_MEMORY_SCOPE_AGENT);
    __threadfence();                     // release: wbl2 pushes block's stores to coherence point
    if (__hip_atomic_fetch_add(cnt, 1, __ATOMIC_ACQ_REL, __HIP_MEMORY_SCOPE_AGENT) == 31){
      __hip_atomic_store(cnt, 0,    __ATOMIC_RELAXED, __HIP_MEMORY_SCOPE_AGENT);
      __hip_atomic_store(gen, g0+1, __ATOMIC_RELEASE, __HIP_MEMORY_SCOPE_AGENT);
    } else {
      while (__hip_atomic_load(gen, __ATOMIC_RELAXED, __HIP_MEMORY_SCOPE_AGENT) == g0)
        __builtin_amdgcn_s_sleep(2);
    }
    __threadfence();                     // acquire: inv local L2
  }
  __syncthreads();
}

// ---------------- persistent chunk recurrence ----------------
// 256 blocks: mt = bid>>5 (8 x 32 batch rows), ht = bid&31 (32 x 16 h cols).
// 4 waves = 4 gates (i,f,c,o). W held in registers (16 x bf16x8 per wave).
__launch_bounds__(256, 1)
__global__ void k_chunk(const unsigned short* __restrict__ Whall,
                        const unsigned short* __restrict__ P,
                        unsigned short* __restrict__ Hb,   // [2][BB*HH] bf16
                        float* __restrict__ Cst,           // [BB*HH]
                        float* __restrict__ out,
                        int* __restrict__ bar, int t0){
  int tid  = threadIdx.x;
  int bid  = blockIdx.x;
  int mt   = bid >> 5, ht = bid & 31;
  int m0   = mt*32, h0 = ht*16;
  int lane = tid & 63, g = tid >> 6;
  int r16  = lane & 15, kb = (lane >> 4)*8;

  // preload this wave's W slice: gate g, col h0+r16, all K -> 64 VGPRs
  bf16x8 bw[16];
  const unsigned short* Wg = Whall + ((long long)g*HH + h0 + r16)*KK;
#pragma unroll
  for (int kk = 0; kk < 16; kk++)
    bw[kk] = *(const bf16x8*)&Wg[kk*32 + kb];

  // per-thread cell state: elems e = tid*2, tid*2+1 -> row=tid>>3, col=(tid&7)*2
  int urow = tid >> 3, ucol = (tid & 7) * 2;
  int gb = m0 + urow;
  int gh = h0 + ucol;
  float c0 = Cst[(long long)gb*HH + gh];
  float c1 = Cst[(long long)gb*HH + gh + 1];

  const unsigned short* P0  = P;
  const unsigned short* P1  = P + 1*CHSZ;
  const unsigned short* P2  = P + 2*CHSZ;
  const unsigned short* P3  = P + 3*CHSZ;
  const unsigned short* P4  = P + 4*CHSZ;
  const unsigned short* P5  = P + 5*CHSZ;
  const unsigned short* P6  = P + 6*CHSZ;
  const unsigned short* P7  = P + 7*CHSZ;

  __shared__ float sg[4][32][16];

  for (int tl = 0; tl < CH; tl++){
    int t = t0 + tl;
    const unsigned short* Hp = Hb + (size_t)(t & 1)*BB*HH;
    unsigned short*       Hn = Hb + (size_t)((t & 1)^1)*BB*HH;

    f32x4 acc0 = {}, acc1 = {};
#pragma unroll
    for (int kk = 0; kk < 16; kk++){
      bf16x8 a0 = *(const bf16x8*)&Hp[(long long)(m0      + r16)*KK + kk*32 + kb];
      bf16x8 a1 = *(const bf16x8*)&Hp[(long long)(m0 + 16 + r16)*KK + kk*32 + kb];
      acc0 = __builtin_amdgcn_mfma_f32_16x16x32_bf16(a0, bw[kk], acc0, 0,0,0);
      acc1 = __builtin_amdgcn_mfma_f32_16x16x32_bf16(a1, bw[kk], acc1, 0,0,0);
    }
#pragma unroll
    for (int i = 0; i < 4; i++){
      sg[g][     (lane>>4)*4 + i][r16] = acc0[i];
      sg[g][16 + (lane>>4)*4 + i][r16] = acc1[i];
    }
    __syncthreads();

    long long prow = ((long long)tl*BB + gb)*HH + gh;
    unsigned int u0 = *(const unsigned int*)&P0[prow];
    unsigned int u1 = *(const unsigned int*)&P1[prow];
    unsigned int u2 = *(const unsigned int*)&P2[prow];
    unsigned int u3 = *(const unsigned int*)&P3[prow];
    unsigned int u4 = *(const unsigned int*)&P4[prow];
    unsigned int u5 = *(const unsigned int*)&P5[prow];
    unsigned int u6 = *(const unsigned int*)&P6[prow];
    unsigned int u7 = *(const unsigned int*)&P7[prow];

    float hn0, hn1;
#pragma unroll
    for (int j = 0; j < 2; j++){
      float it = sigf(bf2f((unsigned short)(j ? u0>>16 : u0)) + sg[0][urow][ucol+j]);
      float ft = sigf(bf2f((unsigned short)(j ? u1>>16 : u1)) + sg[1][urow][ucol+j]);
      float jj = tanhf_(bf2f((unsigned short)(j ? u2>>16 : u2)) + sg[2][urow][ucol+j]);
      float ot = sigf(bf2f((unsigned short)(j ? u7>>16 : u7)) + sg[3][urow][ucol+j]);
      float T1 = sigf(bf2f((unsigned short)(j ? u3>>16 : u3)));
      float T2 = sigf(bf2f((unsigned short)(j ? u4>>16 : u4)));
      float D1 = sigf(bf2f((unsigned short)(j ? u5>>16 : u5)));
      float D2 = sigf(bf2f((unsigned short)(j ? u6>>16 : u6)));
      float c  = j ? c1 : c0;
      float fc = ft*c, ij = it*jj;
      float chat = fc + ij*T1*D1;
      float cnew = fc + ij*T2*D2;
      float hn = ot * tanhf_(chat);
      if (j){ c1 = cnew; hn1 = hn; } else { c0 = cnew; hn0 = hn; }
    }
    *(unsigned int*)&Hn[(long long)gb*HH + gh] =
        (unsigned int)f2bf(hn0) | ((unsigned int)f2bf(hn1) << 16);
    float2 o2; o2.x = hn0; o2.y = hn1;
    *(float2*)&out[((long long)gb*SS + t)*HH + gh] = o2;
    if (t == SS-1){
      float2 h2; h2.x = hn0; h2.y = hn1;
      float2 c2; c2.x = c0;  c2.y = c1;
      *(float2*)&out[(long long)MM*HH + (long long)gb*HH + gh] = h2;
      *(float2*)&out[(long long)MM*HH + (long long)BB*HH + (long long)gb*HH + gh] = c2;
    }
    groupbar(bar, mt);   // Hn visible to all 32 blocks of this mt group
  }
  Cst[(long long)gb*HH + gh]     = c0;
  Cst[(long long)gb*HH + gh + 1] = c1;
}

extern "C" void kernel_launch(void* const* d_in, const int* in_sizes, int n_in,
                              void* d_out, int out_size, void* d_ws, size_t ws_size,
                              hipStream_t stream){
  const float* in = (const float*)d_in[0];

  // workspace carve (~83 MB)
  unsigned short* Wtall = (unsigned short*)d_ws;          // 12*512*512 bf16
  unsigned short* Xb    = Wtall + 12LL*512*512;           // CHROWS*KK bf16
  unsigned short* P     = Xb + (long long)CHROWS*KK;      // 8 * CHSZ bf16
  float* Cst = (float*)(P + 8*CHSZ);                      // BB*HH fp32
  unsigned short* Hb = (unsigned short*)(Cst + (long long)BB*HH);  // 2 buffers
  int* bar = (int*)(Hb + 2LL*BB*HH);                      // 8 groups * 64 ints

  hipMemsetAsync(Cst, 0, (size_t)BB*HH*4, stream);
  hipMemsetAsync(Hb,  0, (size_t)2*BB*HH*2, stream);
  hipMemsetAsync(bar, 0, (size_t)8*64*4, stream);

  Ptr12 pw;
  pw.p[0]  = (const float*)d_in[1];   // Wxi
  pw.p[1]  = (const float*)d_in[4];   // Wxf
  pw.p[2]  = (const float*)d_in[7];   // Wxc
  pw.p[3]  = (const float*)d_in[10];  // Wxt1
  pw.p[4]  = (const float*)d_in[13];  // Wxt2
  pw.p[5]  = (const float*)d_in[16];  // Wxd1
  pw.p[6]  = (const float*)d_in[19];  // Wxd2
  pw.p[7]  = (const float*)d_in[22];  // Wxo
  pw.p[8]  = (const float*)d_in[2];   // Whi
  pw.p[9]  = (const float*)d_in[5];   // Whf
  pw.p[10] = (const float*)d_in[8];   // Whc
  pw.p[11] = (const float*)d_in[23];  // Who
  k_pack_w<<<dim3(64,12), 256, 0, stream>>>(pw, Wtall);

  EpiArgs ea;
  ea.b0 = (const float*)d_in[3];  ea.b1 = (const float*)d_in[6];
  ea.b2 = (const float*)d_in[9];  ea.b3 = (const float*)d_in[12];
  ea.b4 = (const float*)d_in[15]; ea.b5 = (const float*)d_in[18];
  ea.b6 = (const float*)d_in[21]; ea.b7 = (const float*)d_in[26];
  ea.Wt1 = (const float*)d_in[11]; ea.Wt2 = (const float*)d_in[14];
  ea.Wd1 = (const float*)d_in[17]; ea.Wd2 = (const float*)d_in[20];
  ea.Wto = (const float*)d_in[24]; ea.Wdo = (const float*)d_in[25];

  const unsigned short* Whall = Wtall + 8LL*512*512;
  float* out = (float*)d_out;

  for (int ck = 0; ck < NCHUNK; ck++){
    int t0 = ck*CH;
    k_pack_x<<<2048, 256, 0, stream>>>(in, (unsigned int*)Xb, t0);
    k_gemm1<<<dim3(32, CHROWS/128), 256, 0, stream>>>(Xb, Wtall, P, ea, in, t0);

    const unsigned short* WhA = Whall;
    const unsigned short* PA  = P;
    unsigned short* HbA = Hb;
    float* CstA = Cst;
    float* outA = out;
    int*   barA = bar;
    int    t0v  = t0;
    void* args[7] = {&WhA, &PA, &HbA, &CstA, &outA, &barA, &t0v};
    hipError_t e = hipLaunchCooperativeKernel((void*)k_chunk, dim3(256), dim3(256),
                                              args, 0, stream);
    if (e != hipSuccess){
      // fallback: plain launch (256 blocks on 256 CUs are co-resident)
      k_chunk<<<256, 256, 0, stream>>>(WhA, PA, HbA, CstA, outA, barA, t0v);
    }
  }
}

// Round 5
// 2142.554 us; speedup vs baseline: 3.6180x; 3.6180x over previous
//
#include <hip/hip_runtime.h>
#include <hip/hip_bf16.h>

#define BB 256
#define SS 256
#define HH 512
#define KK 512
#define MM (BB*SS)            // 65536
#define CH 32                 // timesteps per chunk
#define NCHUNK (SS/CH)        // 8
#define CHROWS (CH*BB)        // 8192 rows per chunk GEMM
#define CHSZ ((long long)CHROWS*HH)   // elements per P slot per chunk

typedef __attribute__((ext_vector_type(4))) float f32x4;
typedef __attribute__((ext_vector_type(8))) short bf16x8;   // 8 bf16 in 4 VGPRs
typedef __attribute__((ext_vector_type(4))) int  int4v;

__device__ __forceinline__ float bf2f(unsigned short u){
  union { unsigned int i; float f; } w; w.i = ((unsigned int)u) << 16; return w.f;
}
__device__ __forceinline__ unsigned short f2bf(float f){
  union { float f; unsigned int i; } w; w.f = f;
  unsigned int x = w.i;
  x += 0x7fff + ((x >> 16) & 1);   // RNE
  return (unsigned short)(x >> 16);
}
__device__ __forceinline__ float sigf(float x){ return 1.f/(1.f+__expf(-x)); }
__device__ __forceinline__ float tanhf_(float x){
  x = fminf(fmaxf(x, -15.f), 15.f);
  float a = __expf(2.f*x);
  return (a - 1.f)/(a + 1.f);
}
__device__ __forceinline__ void gload16(const void* g, void* l){
  __builtin_amdgcn_global_load_lds(
      (const __attribute__((address_space(1))) unsigned int*)g,
      (__attribute__((address_space(3))) unsigned int*)l, 16, 0, 0);
}

// ---------------- pack x chunk -> bf16 [tl*BB+b][c] ----------------
__global__ void k_pack_x(const float* __restrict__ in, unsigned int* __restrict__ Xb32,
                         int t0){
  const long long tot2 = (long long)CHROWS*256;
  for (long long idx = (long long)blockIdx.x*blockDim.x + threadIdx.x; idx < tot2;
       idx += (long long)gridDim.x*blockDim.x){
    int r  = (int)(idx >> 8);        // tl*BB + b
    int c2 = (int)(idx & 255);       // column pair
    int b  = r & 255, tl = r >> 8;
    const float* src = in + ((long long)b*SS + t0 + tl)*514 + 2 + c2*2;
    float2 v = *(const float2*)src;
    unsigned int lo = f2bf(v.x), hi = f2bf(v.y);
    Xb32[(long long)r*256 + c2] = lo | (hi << 16);
  }
}

// ---------------- pack 12 weights, transposed to [n][k] bf16 ----------------
struct Ptr12 { const float* p[12]; };
__global__ void k_pack_w(Ptr12 ws, unsigned short* __restrict__ Wtall){
  int g = blockIdx.y;
  const float* W = ws.p[g];
  for (int idx = blockIdx.x*blockDim.x + threadIdx.x; idx < 512*512;
       idx += gridDim.x*blockDim.x){
    int n = idx >> 9, k = idx & 511;
    Wtall[(long long)g*262144 + idx] = f2bf(W[k*512 + n]);
  }
}

// ---------------- chunk GEMM, m97 structure: 128x128 tile, BK=32, global_load_lds ----------------
struct EpiArgs {
  const float *b0,*b1,*b2,*b3,*b4,*b5,*b6,*b7;
  const float *Wt1,*Wt2,*Wd1,*Wd2,*Wto,*Wdo;
};

__launch_bounds__(256)
__global__ void k_gemm1(const unsigned short* __restrict__ Xb,
                        const unsigned short* __restrict__ Wtall,
                        unsigned short* __restrict__ P,
                        EpiArgs ea, const float* __restrict__ in, int t0){
  __shared__ unsigned short As[128*32];   // [row][k] linear, 8 KB
  __shared__ unsigned short Bs[128*32];
  int tid  = threadIdx.x;
  int m0   = blockIdx.y * 128;
  int n0   = blockIdx.x * 128;         // column in 8*512 concat space
  int g    = n0 >> 9;
  int lane = tid & 63, w = tid >> 6;
  int wr = w >> 1, wc = w & 1;
  int r16  = lane & 15, kb = (lane >> 4) * 8;

  f32x4 acc[4][4] = {};
  for (int k0 = 0; k0 < KK; k0 += 32){
    __syncthreads();
#pragma unroll
    for (int q = 0; q < 2; q++){
      int idx = q*256 + tid;
      int row = idx >> 2, ko = (idx & 3) * 8;
      gload16(Xb    + (long long)(m0+row)*KK + k0 + ko, As + idx*8);
      gload16(Wtall + (long long)(n0+row)*KK + k0 + ko, Bs + idx*8);
    }
    __syncthreads();
    bf16x8 a[4], b[4];
#pragma unroll
    for (int m = 0; m < 4; m++) a[m] = *(const bf16x8*)&As[(wr*64 + m*16 + r16)*32 + kb];
#pragma unroll
    for (int n = 0; n < 4; n++) b[n] = *(const bf16x8*)&Bs[(wc*64 + n*16 + r16)*32 + kb];
#pragma unroll
    for (int m = 0; m < 4; m++)
#pragma unroll
      for (int n = 0; n < 4; n++)
        acc[m][n] = __builtin_amdgcn_mfma_f32_16x16x32_bf16(a[m], b[n], acc[m][n], 0,0,0);
  }

  const float* biasp = (g==0)?ea.b0:(g==1)?ea.b1:(g==2)?ea.b2:(g==3)?ea.b3:
                       (g==4)?ea.b4:(g==5)?ea.b5:(g==6)?ea.b6:ea.b7;
  unsigned short* Pg = P + (long long)g*CHSZ;

  float bias_n[4], wt_a[4], wt_b[4];
#pragma unroll
  for (int n = 0; n < 4; n++){
    int h = (n0 + wc*64 + n*16 + r16) & 511;
    bias_n[n] = biasp[h];
    if (g == 3)      wt_a[n] = ea.Wt1[h];
    else if (g == 4) wt_a[n] = ea.Wt2[h];
    else if (g == 5) wt_a[n] = ea.Wd1[h];
    else if (g == 6) wt_a[n] = ea.Wd2[h];
    else if (g == 7){ wt_a[n] = ea.Wto[h]; wt_b[n] = ea.Wdo[h]; }
  }
#pragma unroll
  for (int m = 0; m < 4; m++)
#pragma unroll
    for (int i = 0; i < 4; i++){
      int rr = m0 + wr*64 + m*16 + (lane>>4)*4 + i;   // C/D row=(lane>>4)*4+reg
      float tv = 0.f, dv = 0.f;
      if (g >= 3){
        int b_ = rr & 255, tl = rr >> 8;
        long long inrow = ((long long)b_*SS + t0 + tl)*514;
        tv = in[inrow]; dv = in[inrow + 1];
      }
#pragma unroll
      for (int n = 0; n < 4; n++){
        int h = (n0 + wc*64 + n*16 + r16) & 511;
        float v = acc[m][n][i] + bias_n[n];
        if (g == 7)      v += tv*wt_a[n] + dv*wt_b[n];
        else if (g >= 3) v += sigf(((g==5||g==6) ? dv : tv) * wt_a[n]);
        Pg[(long long)rr*HH + h] = f2bf(v);
      }
    }
}

// ---------------- fence-free per-mt-group barrier (32 blocks), monotonic counter ----------------
// bidx = global barrier-call index (bbase + tl), accounts for skipped last-step barriers.
// All cross-block data uses sc0sc1 (LLC-coherent) ops; __syncthreads' vmcnt(0) drain
// completes them at the LLC before the barrier add. No L2 wb/inv anywhere.
__device__ __forceinline__ void groupbar(int* bar, int mt, int bidx){
  __syncthreads();                       // drains vmcnt: sc-stores complete at LLC
  if (threadIdx.x == 0){
    int* cnt = bar + mt*64;
    __hip_atomic_fetch_add(cnt, 1, __ATOMIC_RELAXED, __HIP_MEMORY_SCOPE_AGENT);
    while (__hip_atomic_load(cnt, __ATOMIC_RELAXED, __HIP_MEMORY_SCOPE_AGENT) < 32*(bidx+1))
      __builtin_amdgcn_s_sleep(1);
  }
  __syncthreads();
}

// ---------------- persistent chunk recurrence ----------------
// 256 blocks: mt = bid>>5 (8 groups x 32 batch rows), ht = bid&31 (32 x 16 h cols).
// 4 waves = 4 gates (i,f,c,o). W in registers. H exchanged via LLC (sc0sc1).
__launch_bounds__(256, 1)
__global__ void k_chunk(const unsigned short* __restrict__ Whall,
                        const unsigned short* __restrict__ P,
                        unsigned short* __restrict__ Hb,   // [2][BB*HH] bf16
                        float* __restrict__ Cst,           // [BB*HH]
                        float* __restrict__ out,
                        int* __restrict__ bar, int t0, int bbase){
  __shared__ int4v Hlds4[32*64];          // 32 rows x 1KB, XOR-swizzled (32 KB)
  __shared__ float sg[4][32][16];
  char* Hlds = (char*)Hlds4;

  int tid  = threadIdx.x;
  int bid  = blockIdx.x;
  int mt   = bid >> 5, ht = bid & 31;
  int m0   = mt*32, h0 = ht*16;
  int lane = tid & 63, g = tid >> 6;
  int r16  = lane & 15, kb = (lane >> 4)*8;

  // preload this wave's W slice: gate g, col h0+r16, all K -> 64 VGPRs
  bf16x8 bw[16];
  const unsigned short* Wg = Whall + ((long long)g*HH + h0 + r16)*KK;
#pragma unroll
  for (int kk = 0; kk < 16; kk++)
    bw[kk] = *(const bf16x8*)&Wg[kk*32 + kb];

  // per-thread cell state: row=tid>>3, cols (tid&7)*2, +1
  int urow = tid >> 3, ucol = (tid & 7) * 2;
  int gb = m0 + urow;
  int gh = h0 + ucol;
  float c0 = Cst[(long long)gb*HH + gh];
  float c1 = Cst[(long long)gb*HH + gh + 1];

  const unsigned short* P0  = P;
  const unsigned short* P1  = P + 1*CHSZ;
  const unsigned short* P2  = P + 2*CHSZ;
  const unsigned short* P3  = P + 3*CHSZ;
  const unsigned short* P4  = P + 4*CHSZ;
  const unsigned short* P5  = P + 5*CHSZ;
  const unsigned short* P6  = P + 6*CHSZ;
  const unsigned short* P7  = P + 7*CHSZ;

  int hr = tid >> 3;    // H-stage row 0..31
  int hc = tid & 7;     // H-stage chunk base

  for (int tl = 0; tl < CH; tl++){
    int t = t0 + tl;
    const unsigned short* Hp = Hb + (size_t)(t & 1)*BB*HH;
    unsigned short*       Hn = Hb + (size_t)((t & 1)^1)*BB*HH;

    // P prefetch (plain loads, independent of H) — overlaps staging latency
    long long prow = ((long long)tl*BB + gb)*HH + gh;
    unsigned int u0 = *(const unsigned int*)&P0[prow];
    unsigned int u1 = *(const unsigned int*)&P1[prow];
    unsigned int u2 = *(const unsigned int*)&P2[prow];
    unsigned int u3 = *(const unsigned int*)&P3[prow];
    unsigned int u4 = *(const unsigned int*)&P4[prow];
    unsigned int u5 = *(const unsigned int*)&P5[prow];
    unsigned int u6 = *(const unsigned int*)&P6[prow];
    unsigned int u7 = *(const unsigned int*)&P7[prow];

    // stage H tile (rows m0..m0+31, LLC-coherent loads) into swizzled LDS
    {
      int4v tmp[8];
#pragma unroll
      for (int j = 0; j < 8; j++){
        const unsigned short* src = Hp + (long long)(m0 + hr)*HH + (hc + j*8)*8;
        asm volatile("global_load_dwordx4 %0, %1, off sc0 sc1"
                     : "=v"(tmp[j]) : "v"(src));
      }
      asm volatile("s_waitcnt vmcnt(0)" ::: "memory");
      __builtin_amdgcn_sched_barrier(0);
#pragma unroll
      for (int j = 0; j < 8; j++){
        int c = hc + j*8;
        *(int4v*)(Hlds + hr*1024 + ((c*16) ^ ((hr & 7) << 4))) = tmp[j];
      }
    }
    __syncthreads();

    f32x4 acc0 = {}, acc1 = {};
#pragma unroll
    for (int kk = 0; kk < 16; kk++){
      int c  = kk*4 + (lane >> 4);
      int sw = (c*16) ^ ((r16 & 7) << 4);
      bf16x8 a0 = *(const bf16x8*)(Hlds + r16*1024        + sw);
      bf16x8 a1 = *(const bf16x8*)(Hlds + (r16+16)*1024   + sw);
      acc0 = __builtin_amdgcn_mfma_f32_16x16x32_bf16(a0, bw[kk], acc0, 0,0,0);
      acc1 = __builtin_amdgcn_mfma_f32_16x16x32_bf16(a1, bw[kk], acc1, 0,0,0);
    }
#pragma unroll
    for (int i = 0; i < 4; i++){
      sg[g][     (lane>>4)*4 + i][r16] = acc0[i];
      sg[g][16 + (lane>>4)*4 + i][r16] = acc1[i];
    }
    __syncthreads();

    float hn0, hn1;
#pragma unroll
    for (int j = 0; j < 2; j++){
      float it = sigf(bf2f((unsigned short)(j ? u0>>16 : u0)) + sg[0][urow][ucol+j]);
      float ft = sigf(bf2f((unsigned short)(j ? u1>>16 : u1)) + sg[1][urow][ucol+j]);
      float jj = tanhf_(bf2f((unsigned short)(j ? u2>>16 : u2)) + sg[2][urow][ucol+j]);
      float ot = sigf(bf2f((unsigned short)(j ? u7>>16 : u7)) + sg[3][urow][ucol+j]);
      float T1 = sigf(bf2f((unsigned short)(j ? u3>>16 : u3)));
      float T2 = sigf(bf2f((unsigned short)(j ? u4>>16 : u4)));
      float D1 = sigf(bf2f((unsigned short)(j ? u5>>16 : u5)));
      float D2 = sigf(bf2f((unsigned short)(j ? u6>>16 : u6)));
      float c  = j ? c1 : c0;
      float fc = ft*c, ij = it*jj;
      float chat = fc + ij*T1*D1;
      float cnew = fc + ij*T2*D2;
      float hn = ot * tanhf_(chat);
      if (j){ c1 = cnew; hn1 = hn; } else { c0 = cnew; hn0 = hn; }
    }
    // H store: LLC-coherent (bypass L1/L2); drained by groupbar's syncthreads
    __hip_atomic_store((unsigned int*)&Hn[(long long)gb*HH + gh],
                       (unsigned int)f2bf(hn0) | ((unsigned int)f2bf(hn1) << 16),
                       __ATOMIC_RELAXED, __HIP_MEMORY_SCOPE_AGENT);
    float2 o2; o2.x = hn0; o2.y = hn1;
    *(float2*)&out[((long long)gb*SS + t)*HH + gh] = o2;
    if (t == SS-1){
      float2 h2; h2.x = hn0; h2.y = hn1;
      float2 c2; c2.x = c0;  c2.y = c1;
      *(float2*)&out[(long long)MM*HH + (long long)gb*HH + gh] = h2;
      *(float2*)&out[(long long)MM*HH + (long long)BB*HH + (long long)gb*HH + gh] = c2;
    }
    if (tl != CH-1) groupbar(bar, mt, bbase + tl);  // last step: launch boundary handles visibility
  }
  Cst[(long long)gb*HH + gh]     = c0;
  Cst[(long long)gb*HH + gh + 1] = c1;
}

extern "C" void kernel_launch(void* const* d_in, const int* in_sizes, int n_in,
                              void* d_out, int out_size, void* d_ws, size_t ws_size,
                              hipStream_t stream){
  const float* in = (const float*)d_in[0];

  // workspace carve (~83 MB)
  unsigned short* Wtall = (unsigned short*)d_ws;          // 12*512*512 bf16
  unsigned short* Xb    = Wtall + 12LL*512*512;           // CHROWS*KK bf16
  unsigned short* P     = Xb + (long long)CHROWS*KK;      // 8 * CHSZ bf16
  float* Cst = (float*)(P + 8*CHSZ);                      // BB*HH fp32
  unsigned short* Hb = (unsigned short*)(Cst + (long long)BB*HH);  // 2 buffers
  int* bar = (int*)(Hb + 2LL*BB*HH);                      // 8 groups * 64 ints

  hipMemsetAsync(Cst, 0, (size_t)BB*HH*4, stream);
  hipMemsetAsync(Hb,  0, (size_t)2*BB*HH*2, stream);
  hipMemsetAsync(bar, 0, (size_t)8*64*4, stream);

  Ptr12 pw;
  pw.p[0]  = (const float*)d_in[1];   // Wxi
  pw.p[1]  = (const float*)d_in[4];   // Wxf
  pw.p[2]  = (const float*)d_in[7];   // Wxc
  pw.p[3]  = (const float*)d_in[10];  // Wxt1
  pw.p[4]  = (const float*)d_in[13];  // Wxt2
  pw.p[5]  = (const float*)d_in[16];  // Wxd1
  pw.p[6]  = (const float*)d_in[19];  // Wxd2
  pw.p[7]  = (const float*)d_in[22];  // Wxo
  pw.p[8]  = (const float*)d_in[2];   // Whi
  pw.p[9]  = (const float*)d_in[5];   // Whf
  pw.p[10] = (const float*)d_in[8];   // Whc
  pw.p[11] = (const float*)d_in[23];  // Who
  k_pack_w<<<dim3(64,12), 256, 0, stream>>>(pw, Wtall);

  EpiArgs ea;
  ea.b0 = (const float*)d_in[3];  ea.b1 = (const float*)d_in[6];
  ea.b2 = (const float*)d_in[9];  ea.b3 = (const float*)d_in[12];
  ea.b4 = (const float*)d_in[15]; ea.b5 = (const float*)d_in[18];
  ea.b6 = (const float*)d_in[21]; ea.b7 = (const float*)d_in[26];
  ea.Wt1 = (const float*)d_in[11]; ea.Wt2 = (const float*)d_in[14];
  ea.Wd1 = (const float*)d_in[17]; ea.Wd2 = (const float*)d_in[20];
  ea.Wto = (const float*)d_in[24]; ea.Wdo = (const float*)d_in[25];

  const unsigned short* Whall = Wtall + 8LL*512*512;
  float* out = (float*)d_out;

  for (int ck = 0; ck < NCHUNK; ck++){
    int t0 = ck*CH;
    k_pack_x<<<2048, 256, 0, stream>>>(in, (unsigned int*)Xb, t0);
    k_gemm1<<<dim3(32, CHROWS/128), 256, 0, stream>>>(Xb, Wtall, P, ea, in, t0);

    const unsigned short* WhA = Whall;
    const unsigned short* PA  = P;
    unsigned short* HbA = Hb;
    float* CstA = Cst;
    float* outA = out;
    int*   barA = bar;
    int    t0v  = t0;
    int    bb0  = ck*(CH-1);     // barrier-call index base (31 calls per chunk)
    void* args[8] = {&WhA, &PA, &HbA, &CstA, &outA, &barA, &t0v, &bb0};
    hipError_t e = hipLaunchCooperativeKernel((void*)k_chunk, dim3(256), dim3(256),
                                              args, 0, stream);
    if (e != hipSuccess){
      // fallback: plain launch (256 blocks on 256 CUs are co-resident)
      k_chunk<<<256, 256, 0, stream>>>(WhA, PA, HbA, CstA, outA, barA, t0v, bb0);
    }
  }
}